// Round 10
// baseline (954.413 us; speedup 1.0000x reference)
//
#include <hip/hip_runtime.h>
#include <hip/hip_bf16.h>
#include <stdint.h>

#define N_NODES 10000
#define N_EDGES 100000
#define HIDDEN  128
#define MUL0    32
#define MUL1    8
#define IN_DIM  56
#define W_NUMEL 1600
#define NTILES  1563          // ceil(100000/64)
#define E_PAD   (NTILES*64)   // 100032

// ws layout (bytes)
#define OFF_BT1  0u            // 128x128 bf16 [n][k]
#define OFF_BT2  32768u        // 1600x128 bf16 [n][k]
#define OFF_NUM  442368u       // 10000x56 f32
#define OFF_DEG  2682368u      // 10000 int
#define OFF_SUM  2722368u      // 72 f32 (+pad)
#define OFF_HEAD 2722656u      // 10000 int
#define OFF_ORD  2762656u      // 100000 int (edge ids sorted by src)
#define ZERO_WORDS ((OFF_SUM + 288u - OFF_NUM) / 4u)   // num(+deg)+sums

typedef __attribute__((ext_vector_type(8))) short s8v;
typedef __attribute__((ext_vector_type(4))) float f4v;

__device__ __forceinline__ ushort f2b(float f) {
  uint32_t u = __float_as_uint(f);
  u += 0x7FFFu + ((u >> 16) & 1u);
  return (ushort)(u >> 16);
}

// weight transpose (LDS-tiled, both sides coalesced) + workspace zeroing.
__global__ __launch_bounds__(256) void prep_kernel(
    const float* __restrict__ fc1_w, const float* __restrict__ fc2_w,
    ushort* __restrict__ Bt1, ushort* __restrict__ Bt2,
    uint* __restrict__ zerop) {
  const int bid = blockIdx.x, tid = threadIdx.x;
  if (bid < 216) {
    __shared__ float tile[32][33];
    const int lx = tid & 31, ly = tid >> 5;
    const float* in; ushort* out; int LDI, n0, k0;
    if (bid < 16) {
      in = fc1_w; out = Bt1; LDI = 128;
      n0 = (bid & 3) * 32; k0 = (bid >> 2) * 32;
    } else {
      int t2 = bid - 16;
      in = fc2_w; out = Bt2; LDI = 1600;
      n0 = (t2 % 50) * 32; k0 = (t2 / 50) * 32;
    }
#pragma unroll
    for (int i = 0; i < 4; ++i) {
      int r = i * 8 + ly;
      tile[r][lx] = in[(size_t)(k0 + r) * LDI + n0 + lx];
    }
    __syncthreads();
#pragma unroll
    for (int i = 0; i < 4; ++i) {
      int r = i * 8 + ly;
      out[(size_t)(n0 + r) * 128 + k0 + lx] = f2b(tile[lx][r]);
    }
  } else {
    uint t = (uint)(bid - 216) * 256u + (uint)tid;
    for (uint i = t; i < ZERO_WORDS; i += 160u * 256u) zerop[i] = 0u;
  }
}

// one-block CSR front-end: LDS degree histogram + exclusive scan ->
// writes deg[] and head[] (atomic cursors for counting sort).
__global__ __launch_bounds__(1024) void scan_kernel(
    const int* __restrict__ edge_index, int* __restrict__ deg,
    int* __restrict__ head) {
  __shared__ int hist[N_NODES];
  __shared__ int part[1024];
  const int t = threadIdx.x;
  for (int i = t; i < N_NODES; i += 1024) hist[i] = 0;
  __syncthreads();
  {
    const int4* ei4 = (const int4*)edge_index;
    for (int i = t; i < N_EDGES / 4; i += 1024) {
      int4 v = ei4[i];
      atomicAdd(&hist[v.x], 1); atomicAdd(&hist[v.y], 1);
      atomicAdd(&hist[v.z], 1); atomicAdd(&hist[v.w], 1);
    }
  }
  __syncthreads();
  const int base = t * 10;  // 1024*10 = 10240 >= 10000
  int s = 0;
#pragma unroll
  for (int i = 0; i < 10; ++i) {
    int idx = base + i;
    if (idx < N_NODES) s += hist[idx];
  }
  part[t] = s;
  __syncthreads();
  for (int off = 1; off < 1024; off <<= 1) {
    int v = (t >= off) ? part[t - off] : 0;
    __syncthreads();
    part[t] += v;
    __syncthreads();
  }
  int run = (t == 0) ? 0 : part[t - 1];
#pragma unroll
  for (int i = 0; i < 10; ++i) {
    int idx = base + i;
    if (idx < N_NODES) {
      int d = hist[idx];
      head[idx] = run; deg[idx] = d; run += d;
    }
  }
}

// counting-sort scatter: edge ids grouped by src
__global__ __launch_bounds__(256) void scatter_kernel(
    const int* __restrict__ edge_index, int* __restrict__ head,
    int* __restrict__ edge_order) {
  int e = blockIdx.x * 256 + threadIdx.x;
  if (e < N_EDGES) {
    int s = edge_index[e];
    int pos = atomicAdd(&head[s], 1);
    edge_order[pos] = e;
  }
}

// fully fused, 8-wave (512-thread) version: each wave owns a 16-column slice
// of the w space (vs 32 before). Per-wave state shrinks so the A ping-pong
// fits with huge register margin (budget 341/wave at 6 waves/SIMD).
// 3 blocks/CU (LDS-bound) -> 24 waves/CU.
__global__ __launch_bounds__(512, 6) void fused_kernel(
    const int* __restrict__ edge_index, const float* __restrict__ node_attr,
    const float* __restrict__ edge_sh, const float* __restrict__ fc1_b,
    const float* __restrict__ fc2_b, const ushort* __restrict__ Bt1,
    const ushort* __restrict__ Bt2, const float* __restrict__ edge_attr,
    const int* __restrict__ edge_order, float* __restrict__ num) {
  // U aliases: (a) 64x128 bf16 swizzled h/ea tile (16 KB)
  //            (b) chunk-12 raw partials [64][67] f32
  //            (c) red2 [8][32][17] (=4352); (d) phase1 redbuf [4][64][17]
  __shared__ float U[4352];
  __shared__ float tps[64 * 57];
  __shared__ float x0s[64][33];
  __shared__ float x1s[64][25];
  __shared__ float c1s[64][9];
  __shared__ float y0s[64];
  __shared__ float y1s[64][3];
  __shared__ int srcs[64];
  __shared__ int dsts[64];
  __shared__ int es[64];
  __shared__ int runStart[66];
  __shared__ int runSrc[64];
  __shared__ int nRunsS;

  const int tid = threadIdx.x;
  const int e0 = blockIdx.x * 64;

  if (tid < 64) {
    int i = e0 + tid;
    int e = (i < N_EDGES) ? edge_order[i] : -1;
    es[tid] = e;
    if (e >= 0) {
      srcs[tid] = edge_index[e];
      dsts[tid] = edge_index[N_EDGES + e];
      float4 sh = *(const float4*)(edge_sh + (size_t)e * 4);
      y0s[tid] = sh.x; y1s[tid][0] = sh.y; y1s[tid][1] = sh.z; y1s[tid][2] = sh.w;
    } else {
      srcs[tid] = -1; dsts[tid] = 0;
      y0s[tid] = 0.f; y1s[tid][0] = 0.f; y1s[tid][1] = 0.f; y1s[tid][2] = 0.f;
    }
  }
  __syncthreads();

  const int wave = tid >> 6, lane = tid & 63, q = lane >> 4, m15 = lane & 15;
  const int qh1 = q >> 1;
  ushort* sT = (ushort*)U;  // 64 rows x 256 B, XOR-swizzled (byte ^ (row&7)<<4)

  // ---- gemm1 B-frags (16 h-cols per wave), issue early ----
  s8v b1f[4];
  {
    const ushort* bp = &Bt1[(size_t)(wave * 16 + m15) * 128 + q * 8];
#pragma unroll
    for (int ki = 0; ki < 4; ++ki) b1f[ki] = *(const s8v*)(bp + ki * 32);
  }

  // ---- stage edge_attr rows -> sT (bf16, swizzled); 8 threads/row ----
  {
    const int el = tid >> 3, r = tid & 7;
    int er = es[el];
    const float* src = edge_attr + (size_t)(er >= 0 ? er : 0) * 128 + r * 16;
    uint swz = (uint)(el & 7) << 4;
    s8v w0, w1;
    if (er >= 0) {
      float4 v0 = *(const float4*)(src);
      float4 v1 = *(const float4*)(src + 4);
      float4 v2 = *(const float4*)(src + 8);
      float4 v3 = *(const float4*)(src + 12);
      w0[0] = (short)f2b(v0.x); w0[1] = (short)f2b(v0.y);
      w0[2] = (short)f2b(v0.z); w0[3] = (short)f2b(v0.w);
      w0[4] = (short)f2b(v1.x); w0[5] = (short)f2b(v1.y);
      w0[6] = (short)f2b(v1.z); w0[7] = (short)f2b(v1.w);
      w1[0] = (short)f2b(v2.x); w1[1] = (short)f2b(v2.y);
      w1[2] = (short)f2b(v2.z); w1[3] = (short)f2b(v2.w);
      w1[4] = (short)f2b(v3.x); w1[5] = (short)f2b(v3.y);
      w1[6] = (short)f2b(v3.z); w1[7] = (short)f2b(v3.w);
    } else {
      w0 = (s8v){0, 0, 0, 0, 0, 0, 0, 0};
      w1 = (s8v){0, 0, 0, 0, 0, 0, 0, 0};
    }
    *(s8v*)((char*)sT + (uint)el * 256 + (((uint)(r * 32)) ^ swz)) = w0;
    *(s8v*)((char*)sT + (uint)el * 256 + (((uint)(r * 32 + 16)) ^ swz)) = w1;
  }

  // ---- run detection ----
  if (tid < 64) {
    int s = srcs[tid];
    bool valid = (s >= 0);
    bool lead = valid && (tid == 0 || s != srcs[tid - 1]);
    unsigned long long lm = __ballot(lead);
    unsigned long long vm = __ballot(valid);
    int pos = __popcll(lm & ((1ull << tid) - 1ull));
    if (lead) { runStart[pos] = tid; runSrc[pos] = s; }
    if (tid == 0) {
      int nr = __popcll(lm);
      nRunsS = nr;
      runStart[nr] = __popcll(vm);
    }
  }

  // ---- coefficient staging (8 threads/row) ----
  {
    const int el = tid >> 3, r = tid & 7;
    const float* xb = node_attr + (size_t)dsts[el] * IN_DIM;
    float4 a0 = *(const float4*)(xb + r * 4);
    x0s[el][r * 4 + 0] = a0.x; x0s[el][r * 4 + 1] = a0.y;
    x0s[el][r * 4 + 2] = a0.z; x0s[el][r * 4 + 3] = a0.w;
    float v0 = xb[32 + r * 3 + 0];
    float v1 = xb[32 + r * 3 + 1];
    float v2 = xb[32 + r * 3 + 2];
    x1s[el][r * 3 + 0] = v0; x1s[el][r * 3 + 1] = v1; x1s[el][r * 3 + 2] = v2;
    c1s[el][r] = 0.57735026919f *
                 (v0 * y1s[el][0] + v1 * y1s[el][1] + v2 * y1s[el][2]);
  }
  __syncthreads();

  // ---- gemm1: h^T tile = Bt1 x ea (16 cols per wave) ----
  {
    f4v hacc[4];
#pragma unroll
    for (int nt = 0; nt < 4; ++nt) hacc[nt] = (f4v){0.f, 0.f, 0.f, 0.f};
    uint swz = (uint)(m15 & 7) << 4;
#pragma unroll
    for (int ki = 0; ki < 4; ++ki) {
      s8v eafk[4];
#pragma unroll
      for (int nt = 0; nt < 4; ++nt)
        eafk[nt] = *(const s8v*)((char*)sT + (uint)(nt * 16 + m15) * 256 +
                                 (((uint)(ki * 64 + q * 16)) ^ swz));
#pragma unroll
      for (int nt = 0; nt < 4; ++nt)
        hacc[nt] = __builtin_amdgcn_mfma_f32_16x16x32_bf16(
            b1f[ki], eafk[nt], hacc[nt], 0, 0, 0);
    }
    __syncthreads();  // all eaf reads done before sT overwrite
    {
      float4 bv = *(const float4*)(fc1_b + wave * 16 + q * 4);
#pragma unroll
      for (int nt = 0; nt < 4; ++nt) {
        uint p0 = (uint)f2b(fmaxf(hacc[nt][0] + bv.x, 0.f)) |
                  ((uint)f2b(fmaxf(hacc[nt][1] + bv.y, 0.f)) << 16);
        uint p1 = (uint)f2b(fmaxf(hacc[nt][2] + bv.z, 0.f)) |
                  ((uint)f2b(fmaxf(hacc[nt][3] + bv.w, 0.f)) << 16);
        uint addr = (uint)(nt * 16 + m15) * 256 +
                    ((((uint)(wave * 16 + q * 4)) * 2) ^ swz);
        *(uint2*)((char*)sT + addr) = make_uint2(p0, p1);
      }
    }
  }
  __syncthreads();  // h tile ready

  // ---- A fragments for chunk loop (from LDS tile) ----
  s8v afrag[4][4];
  {
    uint swz = (uint)(m15 & 7) << 4;
#pragma unroll
    for (int nt = 0; nt < 4; ++nt) {
      int row = nt * 16 + m15;
      int er = es[row];
      uint rb = (uint)row * 256;
#pragma unroll
      for (int ki = 0; ki < 4; ++ki) {
        s8v v = *(const s8v*)((char*)sT + rb + (((uint)(ki * 64 + q * 16)) ^ swz));
        if (er < 0) v = (s8v){0, 0, 0, 0, 0, 0, 0, 0};
        afrag[nt][ki] = v;
      }
    }
  }
  __syncthreads();  // all sT reads done; U free (chunk-12 writes it)

  const ushort* bt2base = &Bt2[(size_t)(wave * 16 + m15) * 128 + q * 8];
  const int wg = wave >> 1;       // u-group for ch<10
  const int wpar = wave & 1;      // j-slice parity

  float y0v[4];
#pragma unroll
  for (int nt = 0; nt < 4; ++nt) y0v[nt] = y0s[nt * 16 + m15];

  f4v out0a[4];   // [nt]; j = wpar*16 + q*4 + rr
  f4v aAccL[4];   // [nt]; j = (q&1)*4 + rr
#pragma unroll
  for (int nt = 0; nt < 4; ++nt) {
    out0a[nt] = (f4v){0.f, 0.f, 0.f, 0.f};
    aAccL[nt] = (f4v){0.f, 0.f, 0.f, 0.f};
  }

#define LOADH(DST, CH)                                                         \
  do {                                                                         \
    const ushort* bp_ = bt2base + (size_t)(CH) * 16384;                        \
    _Pragma("unroll") for (int ki = 0; ki < 4; ++ki)                           \
      DST[ki] = *(const s8v*)(bp_ + ki * 32);                                  \
  } while (0)

#define CHUNKH(SRC, CH)                                                        \
  do {                                                                         \
    f4v accm[4];                                                               \
    _Pragma("unroll") for (int nt = 0; nt < 4; ++nt)                           \
      accm[nt] = (f4v){0.f, 0.f, 0.f, 0.f};                                    \
    _Pragma("unroll") for (int ki = 0; ki < 4; ++ki)                           \
      _Pragma("unroll") for (int nt = 0; nt < 4; ++nt)                         \
        accm[nt] = __builtin_amdgcn_mfma_f32_16x16x32_bf16(                    \
            SRC[ki], afrag[nt][ki], accm[nt], 0, 0, 0);                        \
    if ((CH) < 8) {                                                            \
      _Pragma("unroll") for (int nt = 0; nt < 4; ++nt) {                       \
        float cf = x0s[nt * 16 + m15][(CH) * 4 + wg] * y0v[nt];                \
        _Pragma("unroll") for (int rr = 0; rr < 4; ++rr)                       \
          out0a[nt][rr] += cf * accm[nt][rr];                                  \
      }                                                                        \
    } else if ((CH) < 10) {                                                    \
      _Pragma("unroll") for (int nt = 0; nt < 4; ++nt) {                       \
        float cf = c1s[nt * 16 + m15][((CH) - 8) * 4 + wg];                    \
        _Pragma("unroll") for (int rr = 0; rr < 4; ++rr)                       \
          out0a[nt][rr] += cf * accm[nt][rr];                                  \
      }                                                                        \
    } else {                                                                   \
      int uu = ((CH) - 10) * 16 + wave * 2 + qh1;                              \
      _Pragma("unroll") for (int nt = 0; nt < 4; ++nt) {                       \
        float cf = x0s[nt * 16 + m15][uu];                                     \
        _Pragma("unroll") for (int rr = 0; rr < 4; ++rr)                       \
          aAccL[nt][rr] += cf * accm[nt][rr];                                  \
      }                                                                        \
    }                                                                          \
  } while (0)

  s8v Aa[4], Ab[4];
  LOADH(Aa, 0);
#pragma unroll 1
  for (int ch = 0; ch < 12; ch += 2) {
    LOADH(Ab, ch + 1);
    CHUNKH(Aa, ch);
    if (ch + 2 < 12) LOADH(Aa, ch + 2);
    else if (wave < 4) LOADH(Aa, 12);
    CHUNKH(Ab, ch + 1);
  }

  // ---- chunk 12: w10_1 (cols 0-63 -> waves 0-3) -> raw partials to LDS ----
  if (wave < 4) {
    f4v accm[4];
#pragma unroll
    for (int nt = 0; nt < 4; ++nt) accm[nt] = (f4v){0.f, 0.f, 0.f, 0.f};
#pragma unroll
    for (int ki = 0; ki < 4; ++ki)
#pragma unroll
      for (int nt = 0; nt < 4; ++nt)
        accm[nt] = __builtin_amdgcn_mfma_f32_16x16x32_bf16(
            Aa[ki], afrag[nt][ki], accm[nt], 0, 0, 0);
    int ub = wave * 2 + qh1;               // u index 0..7
#pragma unroll
    for (int nt = 0; nt < 4; ++nt)
#pragma unroll
      for (int rr = 0; rr < 4; ++rr)
        U[(nt * 16 + m15) * 67 + ub * 8 + (q & 1) * 4 + rr] = accm[nt][rr];
  }

  const float alpha = 0.15811388300841897f;

  // aAcc cross-half reduce (sums qh1 parity; u fully contracted later)
#pragma unroll
  for (int nt = 0; nt < 4; ++nt)
#pragma unroll
    for (int rr = 0; rr < 4; ++rr)
      aAccL[nt][rr] += __shfl_xor(aAccL[nt][rr], 32);

  __syncthreads();  // chunk-12 raw partials visible

  // ---- out1 bF part: contract raw partials with x1 (512 items, 1 pass) ----
  {
    int e = tid >> 3, jj = tid & 7;
    float b0 = 0.f, b1 = 0.f, b2 = 0.f;
#pragma unroll
    for (int u = 0; u < 8; ++u) {
      float wv = U[e * 67 + u * 8 + jj];
      b0 += x1s[e][u * 3 + 0] * wv;
      b1 += x1s[e][u * 3 + 1] * wv;
      b2 += x1s[e][u * 3 + 2] * wv;
    }
    float y0e = y0s[e];
    tps[e * 57 + 32 + jj * 3 + 0] = alpha * y0e * b0;
    tps[e * 57 + 32 + jj * 3 + 1] = alpha * y0e * b1;
    tps[e * 57 + 32 + jj * 3 + 2] = alpha * y0e * b2;
  }
  __syncthreads();  // raw-partial reads done; U free

  // ---- out1 aF part via red2 [8][32][17] ----
  float* red2 = U;
  if (lane < 32) {
#pragma unroll
    for (int nt = 0; nt < 4; ++nt)
#pragma unroll
      for (int rr = 0; rr < 4; ++rr)
        red2[(wave * 32 + lane) * 17 + nt * 4 + rr] = aAccL[nt][rr];
  }
  __syncthreads();
  {
    int e = tid >> 3, jj = tid & 7;
    int nt = e >> 4, m15e = e & 15, qh = jj >> 2, rr = jj & 3;
    int k2 = nt * 4 + rr;
    float aF = 0.f;
#pragma unroll
    for (int w = 0; w < 8; ++w)
      aF += red2[(w * 32 + qh * 16 + m15e) * 17 + k2];
#pragma unroll
    for (int m = 0; m < 3; ++m)
      tps[e * 57 + 32 + jj * 3 + m] += alpha * y1s[e][m] * aF;
  }
  __syncthreads();  // red2 reads done; U free

  // ---- phase 1: out0 reduce, two parity sub-phases ([4][64][17]) ----
#pragma unroll
  for (int p = 0; p < 2; ++p) {
    if ((wave & 1) == p) {
      int sbase = ((wave >> 1) * 64 + lane) * 17;
#pragma unroll
      for (int nt = 0; nt < 4; ++nt)
#pragma unroll
        for (int rr = 0; rr < 4; ++rr)
          U[sbase + nt * 4 + rr] = out0a[nt][rr];
    }
    __syncthreads();
#pragma unroll
    for (int i = 0; i < 2; ++i) {
      int item = tid + 512 * i;          // 1024 items: e(64) x jj(16)
      int e = item >> 4, jj = item & 15;
      int qq = jj >> 2, rr = jj & 3;
      int slot = qq * 16 + (e & 15);
      int k = (e >> 4) * 4 + rr;
      float s = U[(0 * 64 + slot) * 17 + k] + U[(1 * 64 + slot) * 17 + k] +
                U[(2 * 64 + slot) * 17 + k] + U[(3 * 64 + slot) * 17 + k];
      tps[e * 57 + p * 16 + jj] = alpha * s;
    }
    __syncthreads();
  }

  // ---- one atomic per (run, component) ----
  const int nR = nRunsS;
  for (int k = tid; k < nR * 56; k += 512) {
    int run = k / 56;
    int c = k - run * 56;
    int a = runStart[run], b = runStart[run + 1];
    float sum = 0.f;
    for (int e2 = a; e2 < b; ++e2) sum += tps[e2 * 57 + c];
    atomicAdd(&num[(size_t)runSrc[run] * 56 + c], sum);
  }
#undef CHUNKH
#undef LOADH
}

// out_pre = num/max(deg,1) + node_attr; reduce column stats
__global__ __launch_bounds__(256) void bn_reduce_kernel(
    const float* __restrict__ num, const int* __restrict__ deg,
    const float* __restrict__ node_attr, float* __restrict__ outp,
    float* __restrict__ sums) {
  int n = blockIdx.x * 256 + threadIdx.x;
  float vals[56];
  if (n < N_NODES) {
    float inv = 1.0f / fmaxf((float)deg[n], 1.0f);
    const float4* n4 = (const float4*)(num + (size_t)n * 56);
    const float4* a4 = (const float4*)(node_attr + (size_t)n * 56);
    float4* o4 = (float4*)(outp + (size_t)n * 56);
#pragma unroll
    for (int o = 0; o < 14; ++o) {
      float4 x = n4[o], y = a4[o];
      float4 w;
      w.x = x.x * inv + y.x; w.y = x.y * inv + y.y;
      w.z = x.z * inv + y.z; w.w = x.w * inv + y.w;
      o4[o] = w;
      vals[o * 4 + 0] = w.x; vals[o * 4 + 1] = w.y;
      vals[o * 4 + 2] = w.z; vals[o * 4 + 3] = w.w;
    }
  } else {
#pragma unroll
    for (int o = 0; o < 56; ++o) vals[o] = 0.f;
  }
  int lane = threadIdx.x & 63;
#pragma unroll
  for (int o = 0; o < 32; ++o) {
    float a = vals[o], b = vals[o] * vals[o];
#pragma unroll
    for (int m = 1; m < 64; m <<= 1) { a += __shfl_xor(a, m); b += __shfl_xor(b, m); }
    if (lane == 0) { atomicAdd(&sums[o], a); atomicAdd(&sums[32 + o], b); }
  }
#pragma unroll
  for (int w = 0; w < 8; ++w) {
    float b = vals[32 + w * 3] * vals[32 + w * 3] +
              vals[32 + w * 3 + 1] * vals[32 + w * 3 + 1] +
              vals[32 + w * 3 + 2] * vals[32 + w * 3 + 2];
#pragma unroll
    for (int m = 1; m < 64; m <<= 1) b += __shfl_xor(b, m);
    if (lane == 0) atomicAdd(&sums[64 + w], b);
  }
}

__global__ __launch_bounds__(256) void bn_apply_kernel(
    float* __restrict__ outp, const float* __restrict__ sums,
    const float* __restrict__ bn_w_s, const float* __restrict__ bn_b_s,
    const float* __restrict__ bn_w_v) {
  int i4 = blockIdx.x * 256 + threadIdx.x;
  if (i4 >= N_NODES * IN_DIM / 4) return;
  float4 v = ((float4*)outp)[i4];
  float r[4] = {v.x, v.y, v.z, v.w};
  int base = i4 * 4;
#pragma unroll
  for (int j = 0; j < 4; ++j) {
    int o = (base + j) % 56;
    if (o < 32) {
      float mean = sums[o] * (1.0f / N_NODES);
      float var = sums[32 + o] * (1.0f / N_NODES) - mean * mean;
      r[j] = (r[j] - mean) * rsqrtf(var + 1e-5f) * bn_w_s[o] + bn_b_s[o];
    } else {
      int w = (o - 32) / 3;
      float vn = sums[64 + w] * (1.0f / (3 * N_NODES));
      r[j] = r[j] * rsqrtf(vn + 1e-5f) * bn_w_v[w];
    }
  }
  ((float4*)outp)[i4] = make_float4(r[0], r[1], r[2], r[3]);
}

extern "C" void kernel_launch(void* const* d_in, const int* in_sizes, int n_in,
                              void* d_out, int out_size, void* d_ws, size_t ws_size,
                              hipStream_t stream) {
  const float* node_attr = (const float*)d_in[0];
  const int* edge_index  = (const int*)d_in[1];
  const float* edge_attr = (const float*)d_in[2];
  const float* edge_sh   = (const float*)d_in[3];
  const float* fc1_w     = (const float*)d_in[4];
  const float* fc1_b     = (const float*)d_in[5];
  const float* fc2_w     = (const float*)d_in[6];
  const float* fc2_b     = (const float*)d_in[7];
  const float* bn_w_s    = (const float*)d_in[8];
  const float* bn_w_v    = (const float*)d_in[9];
  const float* bn_b_s    = (const float*)d_in[10];

  char* ws = (char*)d_ws;
  ushort* Bt1 = (ushort*)(ws + OFF_BT1);
  ushort* Bt2 = (ushort*)(ws + OFF_BT2);
  float* num  = (float*)(ws + OFF_NUM);
  int* deg    = (int*)(ws + OFF_DEG);
  float* sums = (float*)(ws + OFF_SUM);
  int* head   = (int*)(ws + OFF_HEAD);
  int* eord   = (int*)(ws + OFF_ORD);
  float* outp = (float*)d_out;

  prep_kernel<<<376, 256, 0, stream>>>(fc1_w, fc2_w, Bt1, Bt2, (uint*)(ws + OFF_NUM));
  scan_kernel<<<1, 1024, 0, stream>>>(edge_index, deg, head);
  scatter_kernel<<<(N_EDGES + 255) / 256, 256, 0, stream>>>(edge_index, head, eord);
  fused_kernel<<<NTILES, 512, 0, stream>>>(edge_index, node_attr, edge_sh, fc1_b,
                                           fc2_b, Bt1, Bt2, edge_attr, eord, num);
  bn_reduce_kernel<<<(N_NODES + 255) / 256, 256, 0, stream>>>(num, deg, node_attr, outp, sums);
  bn_apply_kernel<<<(N_NODES * IN_DIM / 4 + 255) / 256, 256, 0, stream>>>(outp, sums, bn_w_s, bn_b_s, bn_w_v);
}

// Round 11
// 322.370 us; speedup vs baseline: 2.9606x; 2.9606x over previous
//
#include <hip/hip_runtime.h>
#include <hip/hip_bf16.h>
#include <stdint.h>

#define N_NODES 10000
#define N_EDGES 100000
#define HIDDEN  128
#define MUL0    32
#define MUL1    8
#define IN_DIM  56
#define W_NUMEL 1600
#define NTILES  1563          // ceil(100000/64)
#define E_PAD   (NTILES*64)   // 100032

// ws layout (bytes)
#define OFF_BT1  0u            // 128x128 bf16 [n][k]
#define OFF_BT2  32768u        // 1600x128 bf16 [n][k]
#define OFF_NUM  442368u       // 10000x56 f32
#define OFF_DEG  2682368u      // 10000 int
#define OFF_SUM  2722368u      // 72 f32 (+pad)
#define OFF_HEAD 2722656u      // 10000 int
#define OFF_ORD  2762656u      // 100000 int (edge ids sorted by src)
#define OFF_SRC2 3162656u      // 100000 int (src, sorted order)
#define OFF_DST2 3562656u      // 100000 int (dst, sorted order)
#define OFF_SH2  3962656u      // 100000 float4 (edge_sh, sorted order)
#define NUM_WORDS 560000u      // 10000*56

typedef __attribute__((ext_vector_type(8))) short s8v;
typedef __attribute__((ext_vector_type(4))) float f4v;

__device__ __forceinline__ ushort f2b(float f) {
  uint32_t u = __float_as_uint(f);
  u += 0x7FFFu + ((u >> 16) & 1u);
  return (ushort)(u >> 16);
}

// one kernel, three block roles (branch on blockIdx; barriers block-uniform):
//  blocks 0-53:  weight transpose, 4 LDS-tiled 32x32 tiles each (216 tiles)
//  blocks 54-85: zero num (560000 words)
//  block  86:    zero sums + LDS degree histogram + exclusive scan -> deg, head
__global__ __launch_bounds__(1024) void prep_scan_kernel(
    const float* __restrict__ fc1_w, const float* __restrict__ fc2_w,
    ushort* __restrict__ Bt1, ushort* __restrict__ Bt2,
    const int* __restrict__ edge_index, int* __restrict__ deg,
    int* __restrict__ head, uint* __restrict__ numzero,
    float* __restrict__ sums) {
  __shared__ int sm[11072];   // transpose: 4x1056 floats; scan: hist[10000]+part[1024]
  const int bid = blockIdx.x, tid = threadIdx.x;
  if (bid < 54) {
    float* tilef = (float*)sm;
    const int t = bid * 4 + (tid >> 8);       // tile id 0..215
    const int st = tid & 255;
    const int lx = st & 31, ly = st >> 5;     // ly 0..7
    float* tile = tilef + (tid >> 8) * 1056;  // [32][33]
    const float* in; ushort* out; int LDI, n0, k0;
    if (t < 16) {
      in = fc1_w; out = Bt1; LDI = 128;
      n0 = (t & 3) * 32; k0 = (t >> 2) * 32;
    } else {
      int t2 = t - 16;
      in = fc2_w; out = Bt2; LDI = 1600;
      n0 = (t2 % 50) * 32; k0 = (t2 / 50) * 32;
    }
#pragma unroll
    for (int i = 0; i < 4; ++i) {
      int r = i * 8 + ly;
      tile[r * 33 + lx] = in[(size_t)(k0 + r) * LDI + n0 + lx];
    }
    __syncthreads();
#pragma unroll
    for (int i = 0; i < 4; ++i) {
      int r = i * 8 + ly;
      out[(size_t)(n0 + r) * 128 + k0 + lx] = f2b(tile[lx * 33 + r]);
    }
  } else if (bid < 86) {
    for (uint i = (uint)(bid - 54) * 1024u + tid; i < NUM_WORDS; i += 32u * 1024u)
      numzero[i] = 0u;
  } else {
    if (tid < 72) sums[tid] = 0.f;
    int* hist = sm;
    int* part = sm + 10000;
    for (int i = tid; i < N_NODES; i += 1024) hist[i] = 0;
    __syncthreads();
    {
      const int4* ei4 = (const int4*)edge_index;
      for (int i = tid; i < N_EDGES / 4; i += 1024) {
        int4 v = ei4[i];
        atomicAdd(&hist[v.x], 1); atomicAdd(&hist[v.y], 1);
        atomicAdd(&hist[v.z], 1); atomicAdd(&hist[v.w], 1);
      }
    }
    __syncthreads();
    const int base = tid * 10;  // 1024*10 = 10240 >= 10000
    int s = 0;
#pragma unroll
    for (int i = 0; i < 10; ++i) {
      int idx = base + i;
      if (idx < N_NODES) s += hist[idx];
    }
    part[tid] = s;
    __syncthreads();
    for (int off = 1; off < 1024; off <<= 1) {
      int v = (tid >= off) ? part[tid - off] : 0;
      __syncthreads();
      part[tid] += v;
      __syncthreads();
    }
    int run = (tid == 0) ? 0 : part[tid - 1];
#pragma unroll
    for (int i = 0; i < 10; ++i) {
      int idx = base + i;
      if (idx < N_NODES) {
        int d = hist[idx];
        head[idx] = run; deg[idx] = d; run += d;
      }
    }
  }
}

// counting-sort scatter: edge ids grouped by src; also emits sorted-order
// side arrays so fused's prologue reads are sequential (gathers live here,
// where there are no barriers and latency is hidden by block parallelism).
__global__ __launch_bounds__(256) void scatter_kernel(
    const int* __restrict__ edge_index, const float* __restrict__ edge_sh,
    int* __restrict__ head, int* __restrict__ edge_order,
    int* __restrict__ srcs_s, int* __restrict__ dsts_s,
    float4* __restrict__ sh4_s) {
  int e = blockIdx.x * 256 + threadIdx.x;
  if (e < N_EDGES) {
    int s = edge_index[e];
    int d = edge_index[N_EDGES + e];
    int pos = atomicAdd(&head[s], 1);
    edge_order[pos] = e;
    srcs_s[pos] = s;
    dsts_s[pos] = d;
    sh4_s[pos] = *(const float4*)(edge_sh + (size_t)e * 4);
  }
}

// fully fused: edge_attr -> (GEMM1+relu, LDS-local) -> transposed GEMM2 ->
// in-register TP contraction -> cross-wave reduce -> run-based scatter.
// (256,3), r8-proven spill-free body; prologue now reads sorted side arrays.
__global__ __launch_bounds__(256, 3) void fused_kernel(
    const float* __restrict__ node_attr, const float* __restrict__ fc1_b,
    const float* __restrict__ fc2_b, const ushort* __restrict__ Bt1,
    const ushort* __restrict__ Bt2, const float* __restrict__ edge_attr,
    const int* __restrict__ edge_order, const int* __restrict__ srcs_s,
    const int* __restrict__ dsts_s, const float4* __restrict__ sh4_s,
    float* __restrict__ num) {
  // U aliases: (a) 64x128 bf16 swizzled h/ea tile (16 KB)
  //            (b) chunk-12 raw partials [64][67] f32 (stride-67 vs banks)
  //            (c) phase2 red2 [4][32][17]; (d) phase1 redbuf [4][64][17]
  __shared__ float U[4352];
  __shared__ float tps[64 * 57];
  __shared__ float x0s[64][33];
  __shared__ float x1s[64][25];
  __shared__ float c1s[64][9];
  __shared__ float y0s[64];
  __shared__ float y1s[64][3];
  __shared__ int srcs[64];
  __shared__ int dsts[64];
  __shared__ int es[64];
  __shared__ int runStart[66];
  __shared__ int runSrc[64];
  __shared__ int nRunsS;

  const int tid = threadIdx.x;
  const int e0 = blockIdx.x * 64;

  if (tid < 64) {
    int i = e0 + tid;
    if (i < N_EDGES) {
      es[tid] = edge_order[i];
      srcs[tid] = srcs_s[i];
      dsts[tid] = dsts_s[i];
      float4 sh = sh4_s[i];
      y0s[tid] = sh.x; y1s[tid][0] = sh.y; y1s[tid][1] = sh.z; y1s[tid][2] = sh.w;
    } else {
      es[tid] = -1; srcs[tid] = -1; dsts[tid] = 0;
      y0s[tid] = 0.f; y1s[tid][0] = 0.f; y1s[tid][1] = 0.f; y1s[tid][2] = 0.f;
    }
  }
  __syncthreads();

  const int wave = tid >> 6, lane = tid & 63, q = lane >> 4, m15 = lane & 15;
  const int qh1 = q >> 1;
  ushort* sT = (ushort*)U;  // 64 rows x 256 B, XOR-swizzled (byte ^ (row&7)<<4)

  // ---- gemm1 B-frags from global (issue early, independent) ----
  s8v b1f[2][4];
  {
    const ushort* bp = &Bt1[(size_t)(wave * 32 + m15) * 128 + q * 8];
#pragma unroll
    for (int mt = 0; mt < 2; ++mt)
#pragma unroll
      for (int ki = 0; ki < 4; ++ki)
        b1f[mt][ki] = *(const s8v*)(bp + mt * 16 * 128 + ki * 32);
  }

  // ---- stage edge_attr rows -> sT (bf16, swizzled) ----
  {
    const int el = tid >> 2, r = tid & 3;
    int er = es[el];
    const float* src = edge_attr + (size_t)(er >= 0 ? er : 0) * 128 + r * 32;
    uint swz = (uint)(el & 7) << 4;
#pragma unroll
    for (int i = 0; i < 4; ++i) {
      s8v w;
      if (er >= 0) {
        float4 v0 = *(const float4*)(src + i * 8);
        float4 v1 = *(const float4*)(src + i * 8 + 4);
        w[0] = (short)f2b(v0.x); w[1] = (short)f2b(v0.y);
        w[2] = (short)f2b(v0.z); w[3] = (short)f2b(v0.w);
        w[4] = (short)f2b(v1.x); w[5] = (short)f2b(v1.y);
        w[6] = (short)f2b(v1.z); w[7] = (short)f2b(v1.w);
      } else {
        w = (s8v){0, 0, 0, 0, 0, 0, 0, 0};
      }
      uint addr = (uint)el * 256 + (((uint)(r * 64 + i * 16)) ^ swz);
      *(s8v*)((char*)sT + addr) = w;
    }
  }

  // ---- run detection ----
  if (tid < 64) {
    int s = srcs[tid];
    bool valid = (s >= 0);
    bool lead = valid && (tid == 0 || s != srcs[tid - 1]);
    unsigned long long lm = __ballot(lead);
    unsigned long long vm = __ballot(valid);
    int pos = __popcll(lm & ((1ull << tid) - 1ull));
    if (lead) { runStart[pos] = tid; runSrc[pos] = s; }
    if (tid == 0) {
      int nr = __popcll(lm);
      nRunsS = nr;
      runStart[nr] = __popcll(vm);
    }
  }

  // ---- coefficient staging (vector loads; c1 from registers) ----
  {
    const int el = tid >> 2, r = tid & 3;
    const float* xb = node_attr + (size_t)dsts[el] * IN_DIM;
    float4 a0 = *(const float4*)(xb + r * 8);
    float4 a1 = *(const float4*)(xb + r * 8 + 4);
    x0s[el][r * 8 + 0] = a0.x; x0s[el][r * 8 + 1] = a0.y;
    x0s[el][r * 8 + 2] = a0.z; x0s[el][r * 8 + 3] = a0.w;
    x0s[el][r * 8 + 4] = a1.x; x0s[el][r * 8 + 5] = a1.y;
    x0s[el][r * 8 + 6] = a1.z; x0s[el][r * 8 + 7] = a1.w;
    float2 v0 = *(const float2*)(xb + 32 + r * 6);
    float2 v1 = *(const float2*)(xb + 32 + r * 6 + 2);
    float2 v2 = *(const float2*)(xb + 32 + r * 6 + 4);
    x1s[el][r * 6 + 0] = v0.x; x1s[el][r * 6 + 1] = v0.y;
    x1s[el][r * 6 + 2] = v1.x; x1s[el][r * 6 + 3] = v1.y;
    x1s[el][r * 6 + 4] = v2.x; x1s[el][r * 6 + 5] = v2.y;
    float w0 = y1s[el][0], w1 = y1s[el][1], w2 = y1s[el][2];
    c1s[el][r * 2 + 0] = 0.57735026919f * (v0.x * w0 + v0.y * w1 + v1.x * w2);
    c1s[el][r * 2 + 1] = 0.57735026919f * (v1.y * w0 + v2.x * w1 + v2.y * w2);
  }
  __syncthreads();

  // ---- gemm1: h^T tile = Bt1 x ea (per-ki eaf keeps reg peak low) ----
  {
    f4v hacc[2][4];
#pragma unroll
    for (int mt = 0; mt < 2; ++mt)
#pragma unroll
      for (int nt = 0; nt < 4; ++nt) hacc[mt][nt] = (f4v){0.f, 0.f, 0.f, 0.f};
    uint swz = (uint)(m15 & 7) << 4;
#pragma unroll
    for (int ki = 0; ki < 4; ++ki) {
      s8v eafk[4];
#pragma unroll
      for (int nt = 0; nt < 4; ++nt)
        eafk[nt] = *(const s8v*)((char*)sT + (uint)(nt * 16 + m15) * 256 +
                                 (((uint)(ki * 64 + q * 16)) ^ swz));
#pragma unroll
      for (int mt = 0; mt < 2; ++mt)
#pragma unroll
        for (int nt = 0; nt < 4; ++nt)
          hacc[mt][nt] = __builtin_amdgcn_mfma_f32_16x16x32_bf16(
              b1f[mt][ki], eafk[nt], hacc[mt][nt], 0, 0, 0);
    }
    __syncthreads();  // all eaf reads done before sT overwrite
#pragma unroll
    for (int mt = 0; mt < 2; ++mt) {
      float4 bv = *(const float4*)(fc1_b + wave * 32 + mt * 16 + q * 4);
#pragma unroll
      for (int nt = 0; nt < 4; ++nt) {
        uint p0 = (uint)f2b(fmaxf(hacc[mt][nt][0] + bv.x, 0.f)) |
                  ((uint)f2b(fmaxf(hacc[mt][nt][1] + bv.y, 0.f)) << 16);
        uint p1 = (uint)f2b(fmaxf(hacc[mt][nt][2] + bv.z, 0.f)) |
                  ((uint)f2b(fmaxf(hacc[mt][nt][3] + bv.w, 0.f)) << 16);
        uint addr = (uint)(nt * 16 + m15) * 256 +
                    ((((uint)(wave * 32 + mt * 16 + q * 4)) * 2) ^ swz);
        *(uint2*)((char*)sT + addr) = make_uint2(p0, p1);
      }
    }
  }
  __syncthreads();  // h tile ready

  // ---- A fragments for chunk loop (from LDS tile) ----
  s8v afrag[4][4];
  {
    uint swz = (uint)(m15 & 7) << 4;
#pragma unroll
    for (int nt = 0; nt < 4; ++nt) {
      int row = nt * 16 + m15;
      int er = es[row];
      uint rb = (uint)row * 256;
#pragma unroll
      for (int ki = 0; ki < 4; ++ki) {
        s8v v = *(const s8v*)((char*)sT + rb + (((uint)(ki * 64 + q * 16)) ^ swz));
        if (er < 0) v = (s8v){0, 0, 0, 0, 0, 0, 0, 0};
        afrag[nt][ki] = v;
      }
    }
  }
  __syncthreads();  // all sT reads done; U is free (chunk-12 writes it)

  const ushort* bt2base = &Bt2[(size_t)(wave * 32 + m15) * 128 + q * 8];

  float y0v[4];
#pragma unroll
  for (int nt = 0; nt < 4; ++nt) y0v[nt] = y0s[nt * 16 + m15];

  f4v out0a[4][2];   // [nt][mt]; j = mt*16 + q*4 + rr
  f4v aAccL[4];      // [nt]; j = (q&1)*4 + rr
#pragma unroll
  for (int nt = 0; nt < 4; ++nt) {
#pragma unroll
    for (int mt = 0; mt < 2; ++mt) out0a[nt][mt] = (f4v){0.f, 0.f, 0.f, 0.f};
    aAccL[nt] = (f4v){0.f, 0.f, 0.f, 0.f};
  }

  // mt-split half-chunk: Am[4]+accm[4] (32 regs transient) instead of 64.
#define HALF(MT, CH)                                                           \
  do {                                                                         \
    s8v Am[4];                                                                 \
    _Pragma("unroll") for (int ki = 0; ki < 4; ++ki)                           \
      Am[ki] = *(const s8v*)(bp + (MT) * 2048 + ki * 32);                      \
    f4v accm[4];                                                               \
    _Pragma("unroll") for (int nt = 0; nt < 4; ++nt)                           \
      accm[nt] = (f4v){0.f, 0.f, 0.f, 0.f};                                    \
    _Pragma("unroll") for (int ki = 0; ki < 4; ++ki)                           \
      _Pragma("unroll") for (int nt = 0; nt < 4; ++nt)                         \
        accm[nt] = __builtin_amdgcn_mfma_f32_16x16x32_bf16(                    \
            Am[ki], afrag[nt][ki], accm[nt], 0, 0, 0);                         \
    if ((CH) < 8) {                                                            \
      _Pragma("unroll") for (int nt = 0; nt < 4; ++nt) {                       \
        float cf = x0s[nt * 16 + m15][(CH) * 4 + wave] * y0v[nt];              \
        _Pragma("unroll") for (int rr = 0; rr < 4; ++rr)                       \
          out0a[nt][MT][rr] += cf * accm[nt][rr];                              \
      }                                                                        \
    } else if ((CH) < 10) {                                                    \
      _Pragma("unroll") for (int nt = 0; nt < 4; ++nt) {                       \
        float cf = c1s[nt * 16 + m15][((CH) - 8) * 4 + wave];                  \
        _Pragma("unroll") for (int rr = 0; rr < 4; ++rr)                       \
          out0a[nt][MT][rr] += cf * accm[nt][rr];                              \
      }                                                                        \
    } else {                                                                   \
      int uu = ((CH) - 10) * 16 + wave * 4 + (MT) * 2 + qh1;                   \
      _Pragma("unroll") for (int nt = 0; nt < 4; ++nt) {                       \
        float cf = x0s[nt * 16 + m15][uu];                                     \
        _Pragma("unroll") for (int rr = 0; rr < 4; ++rr)                       \
          aAccL[nt][rr] += cf * accm[nt][rr];                                  \
      }                                                                        \
    }                                                                          \
  } while (0)

#pragma unroll 1
  for (int ch = 0; ch < 12; ++ch) {
    const ushort* bp = bt2base + (size_t)ch * 16384;
    HALF(0, ch);
    HALF(1, ch);
  }

  // ---- chunk 12: w10_1 -> raw partials to LDS (U as [64][67]) ----
  if (wave < 2) {
    const ushort* bp = bt2base + (size_t)12 * 16384;
#pragma unroll
    for (int mt = 0; mt < 2; ++mt) {
      s8v Am[4];
#pragma unroll
      for (int ki = 0; ki < 4; ++ki)
        Am[ki] = *(const s8v*)(bp + mt * 2048 + ki * 32);
      f4v accm[4];
#pragma unroll
      for (int nt = 0; nt < 4; ++nt) accm[nt] = (f4v){0.f, 0.f, 0.f, 0.f};
#pragma unroll
      for (int ki = 0; ki < 4; ++ki)
#pragma unroll
        for (int nt = 0; nt < 4; ++nt)
          accm[nt] = __builtin_amdgcn_mfma_f32_16x16x32_bf16(
              Am[ki], afrag[nt][ki], accm[nt], 0, 0, 0);
      int ub = wave * 4 + mt * 2 + qh1;      // u index 0..7
#pragma unroll
      for (int nt = 0; nt < 4; ++nt)
#pragma unroll
        for (int rr = 0; rr < 4; ++rr)
          U[(nt * 16 + m15) * 67 + ub * 8 + (q & 1) * 4 + rr] = accm[nt][rr];
    }
  }

  const float alpha = 0.15811388300841897f;

  // aAcc cross-half reduce (registers, any time before phase 2a)
#pragma unroll
  for (int nt = 0; nt < 4; ++nt)
#pragma unroll
    for (int rr = 0; rr < 4; ++rr)
      aAccL[nt][rr] += __shfl_xor(aAccL[nt][rr], 32);

  __syncthreads();  // chunk-12 raw partials visible

  // ---- out1 bF part: contract raw partials with x1 ----
#pragma unroll
  for (int i = 0; i < 2; ++i) {
    int it = tid + 256 * i;             // 512 items: e(64) x jj(8)
    int e = it >> 3, jj = it & 7;
    float b0 = 0.f, b1 = 0.f, b2 = 0.f;
#pragma unroll
    for (int u = 0; u < 8; ++u) {
      float wv = U[e * 67 + u * 8 + jj];
      b0 += x1s[e][u * 3 + 0] * wv;
      b1 += x1s[e][u * 3 + 1] * wv;
      b2 += x1s[e][u * 3 + 2] * wv;
    }
    float y0e = y0s[e];
    tps[e * 57 + 32 + jj * 3 + 0] = alpha * y0e * b0;
    tps[e * 57 + 32 + jj * 3 + 1] = alpha * y0e * b1;
    tps[e * 57 + 32 + jj * 3 + 2] = alpha * y0e * b2;
  }
  __syncthreads();  // raw-partial reads done; U free

  // ---- out1 aF part via red2 ----
  float* red2 = U;    // [4][32][17]
  if (lane < 32) {
#pragma unroll
    for (int nt = 0; nt < 4; ++nt)
#pragma unroll
      for (int rr = 0; rr < 4; ++rr)
        red2[(wave * 32 + lane) * 17 + nt * 4 + rr] = aAccL[nt][rr];
  }
  __syncthreads();
#pragma unroll
  for (int i = 0; i < 2; ++i) {
    int it = tid + 256 * i;             // 512 items: e(64) x jj(8)
    int e = it >> 3, jj = it & 7;
    int nt = e >> 4, m15e = e & 15, qh = jj >> 2, rr = jj & 3;
    int k2 = nt * 4 + rr;
    float aF = red2[(0 * 32 + qh * 16 + m15e) * 17 + k2] +
               red2[(1 * 32 + qh * 16 + m15e) * 17 + k2] +
               red2[(2 * 32 + qh * 16 + m15e) * 17 + k2] +
               red2[(3 * 32 + qh * 16 + m15e) * 17 + k2];
#pragma unroll
    for (int m = 0; m < 3; ++m)
      tps[e * 57 + 32 + jj * 3 + m] += alpha * y1s[e][m] * aF;
  }
  __syncthreads();  // red2 reads done; U free

  // ---- phase 1: reduce out0 partials across waves (two mt sub-phases) ----
#pragma unroll
  for (int mt = 0; mt < 2; ++mt) {
    {
      int sbase = (wave * 64 + lane) * 17;
#pragma unroll
      for (int nt = 0; nt < 4; ++nt)
#pragma unroll
        for (int rr = 0; rr < 4; ++rr)
          U[sbase + nt * 4 + rr] = out0a[nt][mt][rr];
    }
    __syncthreads();
#pragma unroll
    for (int i = 0; i < 4; ++i) {
      int item = tid + 256 * i;          // 1024 items: e(64) x jj(16)
      int e = item >> 4, jj = item & 15;
      int qq = jj >> 2, rr = jj & 3;
      int slot = qq * 16 + (e & 15);
      int k = (e >> 4) * 4 + rr;
      float s = U[(0 * 64 + slot) * 17 + k] + U[(1 * 64 + slot) * 17 + k] +
                U[(2 * 64 + slot) * 17 + k] + U[(3 * 64 + slot) * 17 + k];
      tps[e * 57 + mt * 16 + jj] = alpha * s;
    }
    __syncthreads();
  }

  // ---- one atomic per (run, component) ----
  const int nR = nRunsS;
  for (int k = tid; k < nR * 56; k += 256) {
    int run = k / 56;
    int c = k - run * 56;
    int a = runStart[run], b = runStart[run + 1];
    float sum = 0.f;
    for (int e2 = a; e2 < b; ++e2) sum += tps[e2 * 57 + c];
    atomicAdd(&num[(size_t)runSrc[run] * 56 + c], sum);
  }
#undef HALF
}

// out_pre = num/max(deg,1) + node_attr; reduce column stats
__global__ __launch_bounds__(256) void bn_reduce_kernel(
    const float* __restrict__ num, const int* __restrict__ deg,
    const float* __restrict__ node_attr, float* __restrict__ outp,
    float* __restrict__ sums) {
  int n = blockIdx.x * 256 + threadIdx.x;
  float vals[56];
  if (n < N_NODES) {
    float inv = 1.0f / fmaxf((float)deg[n], 1.0f);
    const float4* n4 = (const float4*)(num + (size_t)n * 56);
    const float4* a4 = (const float4*)(node_attr + (size_t)n * 56);
    float4* o4 = (float4*)(outp + (size_t)n * 56);
#pragma unroll
    for (int o = 0; o < 14; ++o) {
      float4 x = n4[o], y = a4[o];
      float4 w;
      w.x = x.x * inv + y.x; w.y = x.y * inv + y.y;
      w.z = x.z * inv + y.z; w.w = x.w * inv + y.w;
      o4[o] = w;
      vals[o * 4 + 0] = w.x; vals[o * 4 + 1] = w.y;
      vals[o * 4 + 2] = w.z; vals[o * 4 + 3] = w.w;
    }
  } else {
#pragma unroll
    for (int o = 0; o < 56; ++o) vals[o] = 0.f;
  }
  int lane = threadIdx.x & 63;
#pragma unroll
  for (int o = 0; o < 32; ++o) {
    float a = vals[o], b = vals[o] * vals[o];
#pragma unroll
    for (int m = 1; m < 64; m <<= 1) { a += __shfl_xor(a, m); b += __shfl_xor(b, m); }
    if (lane == 0) { atomicAdd(&sums[o], a); atomicAdd(&sums[32 + o], b); }
  }
#pragma unroll
  for (int w = 0; w < 8; ++w) {
    float b = vals[32 + w * 3] * vals[32 + w * 3] +
              vals[32 + w * 3 + 1] * vals[32 + w * 3 + 1] +
              vals[32 + w * 3 + 2] * vals[32 + w * 3 + 2];
#pragma unroll
    for (int m = 1; m < 64; m <<= 1) b += __shfl_xor(b, m);
    if (lane == 0) atomicAdd(&sums[64 + w], b);
  }
}

__global__ __launch_bounds__(256) void bn_apply_kernel(
    float* __restrict__ outp, const float* __restrict__ sums,
    const float* __restrict__ bn_w_s, const float* __restrict__ bn_b_s,
    const float* __restrict__ bn_w_v) {
  int i4 = blockIdx.x * 256 + threadIdx.x;
  if (i4 >= N_NODES * IN_DIM / 4) return;
  float4 v = ((float4*)outp)[i4];
  float r[4] = {v.x, v.y, v.z, v.w};
  int base = i4 * 4;
#pragma unroll
  for (int j = 0; j < 4; ++j) {
    int o = (base + j) % 56;
    if (o < 32) {
      float mean = sums[o] * (1.0f / N_NODES);
      float var = sums[32 + o] * (1.0f / N_NODES) - mean * mean;
      r[j] = (r[j] - mean) * rsqrtf(var + 1e-5f) * bn_w_s[o] + bn_b_s[o];
    } else {
      int w = (o - 32) / 3;
      float vn = sums[64 + w] * (1.0f / (3 * N_NODES));
      r[j] = r[j] * rsqrtf(vn + 1e-5f) * bn_w_v[w];
    }
  }
  ((float4*)outp)[i4] = make_float4(r[0], r[1], r[2], r[3]);
}

extern "C" void kernel_launch(void* const* d_in, const int* in_sizes, int n_in,
                              void* d_out, int out_size, void* d_ws, size_t ws_size,
                              hipStream_t stream) {
  const float* node_attr = (const float*)d_in[0];
  const int* edge_index  = (const int*)d_in[1];
  const float* edge_attr = (const float*)d_in[2];
  const float* edge_sh   = (const float*)d_in[3];
  const float* fc1_w     = (const float*)d_in[4];
  const float* fc1_b     = (const float*)d_in[5];
  const float* fc2_w     = (const float*)d_in[6];
  const float* fc2_b     = (const float*)d_in[7];
  const float* bn_w_s    = (const float*)d_in[8];
  const float* bn_w_v    = (const float*)d_in[9];
  const float* bn_b_s    = (const float*)d_in[10];

  char* ws = (char*)d_ws;
  ushort* Bt1 = (ushort*)(ws + OFF_BT1);
  ushort* Bt2 = (ushort*)(ws + OFF_BT2);
  float* num  = (float*)(ws + OFF_NUM);
  int* deg    = (int*)(ws + OFF_DEG);
  float* sums = (float*)(ws + OFF_SUM);
  int* head   = (int*)(ws + OFF_HEAD);
  int* eord   = (int*)(ws + OFF_ORD);
  int* srcs_s = (int*)(ws + OFF_SRC2);
  int* dsts_s = (int*)(ws + OFF_DST2);
  float4* sh4_s = (float4*)(ws + OFF_SH2);
  float* outp = (float*)d_out;

  prep_scan_kernel<<<87, 1024, 0, stream>>>(fc1_w, fc2_w, Bt1, Bt2, edge_index,
                                            deg, head, (uint*)(ws + OFF_NUM), sums);
  scatter_kernel<<<(N_EDGES + 255) / 256, 256, 0, stream>>>(
      edge_index, edge_sh, head, eord, srcs_s, dsts_s, sh4_s);
  fused_kernel<<<NTILES, 256, 0, stream>>>(node_attr, fc1_b, fc2_b, Bt1, Bt2,
                                           edge_attr, eord, srcs_s, dsts_s,
                                           sh4_s, num);
  bn_reduce_kernel<<<(N_NODES + 255) / 256, 256, 0, stream>>>(num, deg, node_attr, outp, sums);
  bn_apply_kernel<<<(N_NODES * IN_DIM / 4 + 255) / 256, 256, 0, stream>>>(outp, sums, bn_w_s, bn_b_s, bn_w_v);
}